// Round 3
// baseline (805.983 us; speedup 1.0000x reference)
//
#include <hip/hip_runtime.h>
#include <math.h>

#define NTOK 4096   // B*T = 2*2048
#define DM   1024
#define DH   4096
#define NE   8
#define NSLOT (NTOK*2)

typedef unsigned short u16;
typedef __attribute__((ext_vector_type(8))) short shortx8;  // 8 bf16
typedef __attribute__((ext_vector_type(4))) float floatx4;
typedef __attribute__((ext_vector_type(4))) int   intx4;

__device__ __forceinline__ u16 f2bf(float f) {
  union { float f; unsigned u; } c; c.f = f;
  unsigned r = c.u + 0x7fffu + ((c.u >> 16) & 1u);   // RNE
  return (u16)(r >> 16);
}

// async 16B/lane global -> LDS (dest = wave-uniform base + lane*16)
__device__ __forceinline__ void async_cp16(const u16* g, u16* l) {
  __builtin_amdgcn_global_load_lds(
      (const __attribute__((address_space(1))) void*)g,
      (__attribute__((address_space(3))) void*)l, 16, 0, 0);
}

// ---------------- x -> bf16 ----------------
__global__ void cvt_x_kernel(const float* __restrict__ x, u16* __restrict__ xb) {
  int i = (blockIdx.x * 256 + threadIdx.x) * 8;
  float4 v0 = *(const float4*)(x + i);
  float4 v1 = *(const float4*)(x + i + 4);
  u16 tmp[8] = {f2bf(v0.x), f2bf(v0.y), f2bf(v0.z), f2bf(v0.w),
                f2bf(v1.x), f2bf(v1.y), f2bf(v1.z), f2bf(v1.w)};
  *(intx4*)(xb + i) = *(intx4*)tmp;
}

// ---------------- W [E][K][NW] fp32 -> Wt [E][NW][K] bf16 ----------------
template<int K, int NW>
__global__ void transpose_kernel(const float* __restrict__ W, u16* __restrict__ Wt) {
  int e = blockIdx.z;
  const float* Wp = W + (size_t)e * K * NW;
  u16* Wtp = Wt + (size_t)e * K * NW;
  int n = blockIdx.x * 64 + (threadIdx.x & 63);
  int kend = blockIdx.y * 256 + 256;
  for (int k0 = blockIdx.y * 256 + (threadIdx.x >> 6) * 8; k0 < kend; k0 += 32) {
    u16 tmp[8];
#pragma unroll
    for (int j = 0; j < 8; j++) tmp[j] = f2bf(Wp[(size_t)(k0 + j) * NW + n]);
    *(intx4*)(Wtp + (size_t)n * K + k0) = *(intx4*)tmp;
  }
}

// ---------------- router ----------------
__global__ __launch_bounds__(256) void router_kernel(const float* __restrict__ x,
                                                     const float* __restrict__ gw,
                                                     int* __restrict__ eos,
                                                     float* __restrict__ wos) {
  int wave = threadIdx.x >> 6, lane = threadIdx.x & 63;
  int n = blockIdx.x * 4 + wave;
  const float* xr = x + (size_t)n * DM;
  float acc[NE];
#pragma unroll
  for (int e = 0; e < NE; e++) acc[e] = 0.f;
  for (int d = lane; d < DM; d += 64) {
    float xv = xr[d];
#pragma unroll
    for (int e = 0; e < NE; e++) acc[e] += xv * gw[e * DM + d];
  }
#pragma unroll
  for (int e = 0; e < NE; e++) {
    float v = acc[e];
#pragma unroll
    for (int off = 32; off > 0; off >>= 1) v += __shfl_xor(v, off, 64);
    acc[e] = v;
  }
  if (lane == 0) {
    int i0 = 0;
    for (int e = 1; e < NE; e++) if (acc[e] > acc[i0]) i0 = e;
    int i1 = (i0 == 0) ? 1 : 0;
    for (int e = 0; e < NE; e++) { if (e == i0) continue; if (acc[e] > acc[i1]) i1 = e; }
    float e1 = expf(acc[i1] - acc[i0]);
    float w0 = 1.f / (1.f + e1);
    eos[2 * n] = i0;  eos[2 * n + 1] = i1;
    wos[2 * n] = w0;  wos[2 * n + 1] = 1.f - w0;
  }
}

// ---------------- deterministic counting sort ----------------
__global__ __launch_bounds__(256) void build_groups_kernel(
    const int* __restrict__ eos, const float* __restrict__ wos,
    int* __restrict__ goff, int* __restrict__ tok_of_g, float* __restrict__ w_of_g) {
  __shared__ int pref[256][NE];
  __shared__ int tot[NE];
  __shared__ int ebase[NE + 1];
  int t = threadIdx.x;
  int c[NE];
#pragma unroll
  for (int e = 0; e < NE; e++) c[e] = 0;
  for (int i = 0; i < NSLOT / 256; i++) {
    int e = eos[t * (NSLOT / 256) + i];
#pragma unroll
    for (int q = 0; q < NE; q++) if (e == q) c[q]++;
  }
#pragma unroll
  for (int e = 0; e < NE; e++) pref[t][e] = c[e];
  __syncthreads();
  if (t < NE) {
    int run = 0;
    for (int i = 0; i < 256; i++) { int v = pref[i][t]; pref[i][t] = run; run += v; }
    tot[t] = run;
  }
  __syncthreads();
  if (t == 0) {
    int o = 0;
    for (int e = 0; e < NE; e++) { ebase[e] = o; o += tot[e]; }
    ebase[NE] = o;
  }
  __syncthreads();
  int off[NE];
#pragma unroll
  for (int e = 0; e < NE; e++) off[e] = ebase[e] + pref[t][e];
  for (int i = 0; i < NSLOT / 256; i++) {
    int s = t * (NSLOT / 256) + i;
    int e = eos[s];
    int g = 0;
#pragma unroll
    for (int q = 0; q < NE; q++) if (e == q) { g = off[q]; off[q] = g + 1; }
    tok_of_g[g] = s >> 1;
    w_of_g[g] = wos[s];
  }
  if (t <= NE) goff[t] = ebase[t];
}

// ---------------- grouped GEMM: dbuf pipeline + XCD swizzle ----------------
// 1D grid: id -> e = id&7 (XCD pin), then [nb][kseg][mb] (mb fastest: B-tile L2 reuse)
// MODE 0: A=xb gathered rows -> gelu -> h (bf16)
// MODE 1: A=h contiguous rows -> gate-weighted atomicAdd -> out (fp32); bias kseg0 only
template<int K, int NOUT, int MODE, int KSPLIT>
__global__ __launch_bounds__(256) void moe_gemm(
    const u16* __restrict__ A, const u16* __restrict__ Wt, const float* __restrict__ bias,
    const int* __restrict__ goff, const int* __restrict__ tok_of_g,
    const float* __restrict__ w_of_g,
    u16* __restrict__ Hout, float* __restrict__ Out) {
  const int KLEN = K / KSPLIT;
  int id = blockIdx.x;
  int e = id & 7;
  int s = id >> 3;
  int kseg = 0;
  if (KSPLIT > 1) { kseg = s & (KSPLIT - 1); s >>= 1; }   // KSPLIT power of 2
  int mb = s & 31;
  int nb = s >> 5;
  int gb = goff[e];
  int cntE = goff[e + 1] - gb;
  int m0 = mb * 128;
  if (m0 >= cntE) return;
  int mvalid = cntE - m0; if (mvalid > 128) mvalid = 128;
  int gbase = gb + m0;
  int n0 = nb * 128;
  int kbeg = kseg * KLEN;
  int tid = threadIdx.x;
  int lane = tid & 63, wave = tid >> 6;

  __shared__ __align__(16) u16 As0[128 * 32], Bs0[128 * 32];
  __shared__ __align__(16) u16 As1[128 * 32], Bs1[128 * 32];

  // staging: wave w covers chunk rows [w*16, w*16+16) and [64+w*16, ...)
  int sr = lane >> 2;
  int sc = (lane & 3) * 8;
  int ra0 = wave * 16 + sr;
  int ra1 = 64 + wave * 16 + sr;
  int ca0 = (ra0 < mvalid) ? ra0 : (mvalid - 1);
  int ca1 = (ra1 < mvalid) ? ra1 : (mvalid - 1);
  const u16 *pa0, *pa1;
  if (MODE == 0) {
    pa0 = A + (size_t)tok_of_g[gbase + ca0] * K + sc;
    pa1 = A + (size_t)tok_of_g[gbase + ca1] * K + sc;
  } else {
    pa0 = A + (size_t)(gbase + ca0) * K + sc;
    pa1 = A + (size_t)(gbase + ca1) * K + sc;
  }
  const u16* wte = Wt + (size_t)e * NOUT * K;
  const u16* pb0 = wte + (size_t)(n0 + ra0) * K + sc;
  const u16* pb1 = wte + (size_t)(n0 + ra1) * K + sc;
  int ldso = wave * 512;

  int wm = wave >> 1, wn = wave & 1;
  int lr = lane & 15, lk = (lane >> 4) * 8;

  floatx4 acc[4][4];
#pragma unroll
  for (int i = 0; i < 4; i++)
#pragma unroll
    for (int j = 0; j < 4; j++) acc[i][j] = (floatx4){0.f, 0.f, 0.f, 0.f};

#define STAGE(k0, AS, BS)                    \
  do {                                       \
    async_cp16(pa0 + (k0), AS + ldso);       \
    async_cp16(pa1 + (k0), AS + 2048 + ldso);\
    async_cp16(pb0 + (k0), BS + ldso);       \
    async_cp16(pb1 + (k0), BS + 2048 + ldso);\
  } while (0)

#define COMPUTE(AS, BS)                                                         \
  do {                                                                          \
    shortx8 af[4], bfr[4];                                                      \
    _Pragma("unroll")                                                           \
    for (int i = 0; i < 4; i++) {                                               \
      af[i]  = *(const shortx8*)&AS[(wm * 64 + i * 16 + lr) * 32 + lk];         \
      bfr[i] = *(const shortx8*)&BS[(wn * 64 + i * 16 + lr) * 32 + lk];         \
    }                                                                           \
    _Pragma("unroll")                                                           \
    for (int i = 0; i < 4; i++)                                                 \
      _Pragma("unroll")                                                         \
      for (int j = 0; j < 4; j++)                                               \
        acc[i][j] = __builtin_amdgcn_mfma_f32_16x16x32_bf16(af[i], bfr[j],      \
                                                            acc[i][j], 0, 0, 0);\
  } while (0)

  // pipeline: stage k+32 while computing k (copies in flight during MFMA;
  // the barrier's vmcnt drain then overlaps with compute)
  STAGE(kbeg, As0, Bs0);
  __syncthreads();
  int k0 = kbeg;
  for (; k0 + 64 < kbeg + KLEN; k0 += 64) {
    STAGE(k0 + 32, As1, Bs1);
    COMPUTE(As0, Bs0);
    __syncthreads();
    STAGE(k0 + 64, As0, Bs0);
    COMPUTE(As1, Bs1);
    __syncthreads();
  }
  STAGE(k0 + 32, As1, Bs1);
  COMPUTE(As0, Bs0);
  __syncthreads();
  COMPUTE(As1, Bs1);

  const float* bp = bias + (size_t)e * NOUT + n0;
  if (MODE == 0) {
#pragma unroll
    for (int i = 0; i < 4; i++) {
      int rowb = wm * 64 + i * 16 + (lane >> 4) * 4;
#pragma unroll
      for (int r = 0; r < 4; r++) {
        int grow = rowb + r;
        if (grow < mvalid) {
          size_t base = (size_t)(gbase + grow) * NOUT + n0;
#pragma unroll
          for (int j = 0; j < 4; j++) {
            int col = wn * 64 + j * 16 + lr;
            float v = acc[i][j][r] + bp[col];
            v = 0.5f * v * (1.f + erff(v * 0.70710678118654752f));  // exact gelu
            Hout[base + col] = f2bf(v);
          }
        }
      }
    }
  } else {
#pragma unroll
    for (int i = 0; i < 4; i++) {
      int rowb = wm * 64 + i * 16 + (lane >> 4) * 4;
#pragma unroll
      for (int r = 0; r < 4; r++) {
        int grow = rowb + r;
        if (grow < mvalid) {
          int gi = gbase + grow;
          int t = tok_of_g[gi];
          float wg = w_of_g[gi];
          float* orow = Out + (size_t)t * DM + n0;
#pragma unroll
          for (int j = 0; j < 4; j++) {
            int col = wn * 64 + j * 16 + lr;
            float bb = (kseg == 0) ? bp[col] : 0.f;
            atomicAdd(&orow[col], wg * (acc[i][j][r] + bb));
          }
        }
      }
    }
  }
#undef STAGE
#undef COMPUTE
}

extern "C" void kernel_launch(void* const* d_in, const int* in_sizes, int n_in,
                              void* d_out, int out_size, void* d_ws, size_t ws_size,
                              hipStream_t stream) {
  const float* x  = (const float*)d_in[0];
  const float* gw = (const float*)d_in[1];
  const float* w1 = (const float*)d_in[2];
  const float* b1 = (const float*)d_in[3];
  const float* w2 = (const float*)d_in[4];
  const float* b2 = (const float*)d_in[5];
  float* out = (float*)d_out;
  char* ws = (char*)d_ws;

  u16* xb = (u16*)(ws + 0);                       // 8 MB
  u16* wt = (u16*)(ws + 8388608);                 // 64 MB (w1t, then w2t)
  u16* h  = (u16*)(ws + 75497472);                // 64 MB
  char* meta = ws + 142606336;
  int*   eos      = (int*)(meta);
  int*   tok_of_g = (int*)(meta + 32768);
  float* wos      = (float*)(meta + 65536);
  float* w_of_g   = (float*)(meta + 98304);
  int*   goff     = (int*)(meta + 131072);

  hipMemsetAsync(out, 0, (size_t)NTOK * DM * 4, stream);

  cvt_x_kernel<<<NTOK * DM / 8 / 256, 256, 0, stream>>>(x, xb);
  transpose_kernel<DM, DH><<<dim3(DH / 64, DM / 256, NE), 256, 0, stream>>>(w1, wt);
  router_kernel<<<NTOK / 4, 256, 0, stream>>>(x, gw, eos, wos);
  build_groups_kernel<<<1, 256, 0, stream>>>(eos, wos, goff, tok_of_g, w_of_g);
  // GEMM1: 8 experts x (32 nb x 32 mb), expert pinned to XCD via id&7
  moe_gemm<DM, DH, 0, 1><<<NE * 32 * 32, 256, 0, stream>>>(
      xb, wt, b1, goff, tok_of_g, w_of_g, h, nullptr);
  transpose_kernel<DH, DM><<<dim3(DM / 64, DH / 256, NE), 256, 0, stream>>>(w2, wt);
  // GEMM2: 8 experts x (8 nb x 2 kseg x 32 mb), split-K x2
  moe_gemm<DH, DM, 1, 2><<<NE * 8 * 2 * 32, 256, 0, stream>>>(
      h, wt, b2, goff, tok_of_g, w_of_g, nullptr, out);
}

// Round 4
// 685.014 us; speedup vs baseline: 1.1766x; 1.1766x over previous
//
#include <hip/hip_runtime.h>
#include <math.h>

#define NTOK 4096   // B*T = 2*2048
#define DM   1024
#define DH   4096
#define NE   8
#define NSLOT (NTOK*2)
#define TMAX 72     // max compacted (expert, mb) tiles: sum ceil(cnt_e/128) <= 64+7

typedef unsigned short u16;
typedef __attribute__((ext_vector_type(8))) short shortx8;  // 8 bf16
typedef __attribute__((ext_vector_type(4))) float floatx4;
typedef __attribute__((ext_vector_type(4))) int   intx4;

__device__ __forceinline__ u16 f2bf(float f) {
  union { float f; unsigned u; } c; c.f = f;
  unsigned r = c.u + 0x7fffu + ((c.u >> 16) & 1u);   // RNE
  return (u16)(r >> 16);
}

// async 16B/lane global -> LDS (dest = wave-uniform base + lane*16)
__device__ __forceinline__ void async_cp16(const u16* g, u16* l) {
  __builtin_amdgcn_global_load_lds(
      (const __attribute__((address_space(1))) void*)g,
      (__attribute__((address_space(3))) void*)l, 16, 0, 0);
}

// ---------------- x -> bf16 ----------------
__global__ void cvt_x_kernel(const float* __restrict__ x, u16* __restrict__ xb) {
  int i = (blockIdx.x * 256 + threadIdx.x) * 8;
  float4 v0 = *(const float4*)(x + i);
  float4 v1 = *(const float4*)(x + i + 4);
  u16 tmp[8] = {f2bf(v0.x), f2bf(v0.y), f2bf(v0.z), f2bf(v0.w),
                f2bf(v1.x), f2bf(v1.y), f2bf(v1.z), f2bf(v1.w)};
  *(intx4*)(xb + i) = *(intx4*)tmp;
}

// ---------------- W [E][K][NW] fp32 -> Wt [E][NW][K] bf16, LDS-tiled ----------------
// 64x64 tile: coalesced 256B-segment reads, coalesced 128B-segment writes.
template<int K, int NW>
__global__ __launch_bounds__(256) void transpose_kernel(const float* __restrict__ W,
                                                        u16* __restrict__ Wt) {
  __shared__ u16 tile[64][66];   // stride 66 u16 = 132 B
  int e = blockIdx.z;
  int n0 = blockIdx.x * 64, k0 = blockIdx.y * 64;
  int tt = threadIdx.x;
  const float* src = W + (size_t)e * K * NW + (size_t)(k0 + (tt >> 2)) * NW + n0 + (tt & 3) * 16;
  int r = tt >> 2, c4 = (tt & 3) * 16;
  float4 v[4];
#pragma unroll
  for (int i = 0; i < 4; i++) v[i] = *(const float4*)(src + i * 4);
#pragma unroll
  for (int i = 0; i < 4; i++) {
    tile[r][c4 + 4 * i + 0] = f2bf(v[i].x);
    tile[r][c4 + 4 * i + 1] = f2bf(v[i].y);
    tile[r][c4 + 4 * i + 2] = f2bf(v[i].z);
    tile[r][c4 + 4 * i + 3] = f2bf(v[i].w);
  }
  __syncthreads();
  u16* dst = Wt + (size_t)e * NW * K + (size_t)n0 * K + k0;
#pragma unroll
  for (int p = 0; p < 2; p++) {
    int n = (tt >> 3) + p * 32;
    int kc = (tt & 7) * 8;
    u16 o[8];
#pragma unroll
    for (int i = 0; i < 8; i++) o[i] = tile[kc + i][n];
    *(intx4*)(dst + (size_t)n * K + kc) = *(intx4*)o;
  }
}

// ---------------- router ----------------
__global__ __launch_bounds__(256) void router_kernel(const float* __restrict__ x,
                                                     const float* __restrict__ gw,
                                                     int* __restrict__ eos,
                                                     float* __restrict__ wos) {
  int wave = threadIdx.x >> 6, lane = threadIdx.x & 63;
  int n = blockIdx.x * 4 + wave;
  const float* xr = x + (size_t)n * DM;
  float acc[NE];
#pragma unroll
  for (int e = 0; e < NE; e++) acc[e] = 0.f;
  for (int d = lane; d < DM; d += 64) {
    float xv = xr[d];
#pragma unroll
    for (int e = 0; e < NE; e++) acc[e] += xv * gw[e * DM + d];
  }
#pragma unroll
  for (int e = 0; e < NE; e++) {
    float v = acc[e];
#pragma unroll
    for (int off = 32; off > 0; off >>= 1) v += __shfl_xor(v, off, 64);
    acc[e] = v;
  }
  if (lane == 0) {
    int i0 = 0;
    for (int e = 1; e < NE; e++) if (acc[e] > acc[i0]) i0 = e;
    int i1 = (i0 == 0) ? 1 : 0;
    for (int e = 0; e < NE; e++) { if (e == i0) continue; if (acc[e] > acc[i1]) i1 = e; }
    float e1 = expf(acc[i1] - acc[i0]);
    float w0 = 1.f / (1.f + e1);
    eos[2 * n] = i0;  eos[2 * n + 1] = i1;
    wos[2 * n] = w0;  wos[2 * n + 1] = 1.f - w0;
  }
}

// ---------------- counting sort + compacted tile list ----------------
__global__ __launch_bounds__(256) void build_groups_kernel(
    const int* __restrict__ eos, const float* __restrict__ wos,
    int* __restrict__ goff, int* __restrict__ tok_of_g, float* __restrict__ w_of_g,
    int* __restrict__ tiles, int* __restrict__ ntiles) {
  __shared__ int pref[256][NE];
  __shared__ int tot[NE];
  __shared__ int ebase[NE + 1];
  int t = threadIdx.x;
  int c[NE];
#pragma unroll
  for (int e = 0; e < NE; e++) c[e] = 0;
  for (int i = 0; i < NSLOT / 256; i++) {
    int e = eos[t * (NSLOT / 256) + i];
#pragma unroll
    for (int q = 0; q < NE; q++) if (e == q) c[q]++;
  }
#pragma unroll
  for (int e = 0; e < NE; e++) pref[t][e] = c[e];
  __syncthreads();
  if (t < NE) {
    int run = 0;
    for (int i = 0; i < 256; i++) { int v = pref[i][t]; pref[i][t] = run; run += v; }
    tot[t] = run;
  }
  __syncthreads();
  if (t == 0) {
    int o = 0;
    for (int e = 0; e < NE; e++) { ebase[e] = o; o += tot[e]; }
    ebase[NE] = o;
    int nt = 0;
    for (int e = 0; e < NE; e++)
      for (int mb = 0; mb * 128 < tot[e]; mb++) tiles[nt++] = (e << 16) | mb;
    ntiles[0] = nt;
  }
  __syncthreads();
  int off[NE];
#pragma unroll
  for (int e = 0; e < NE; e++) off[e] = ebase[e] + pref[t][e];
  for (int i = 0; i < NSLOT / 256; i++) {
    int s = t * (NSLOT / 256) + i;
    int e = eos[s];
    int g = 0;
#pragma unroll
    for (int q = 0; q < NE; q++) if (e == q) { g = off[q]; off[q] = g + 1; }
    tok_of_g[g] = s >> 1;
    w_of_g[g] = wos[s];
  }
  if (t <= NE) goff[t] = ebase[t];
}

// ---------------- grouped GEMM: compacted tiles, single-buffered (max residency) ----
// grid = (TMAX tiles fastest [B-tile shared by consecutive blocks], nb, kseg)
// MODE 0: A=xb gathered rows -> gelu -> h (bf16)
// MODE 1: A=h contiguous rows -> gate-weighted atomicAdd -> out (fp32); bias kseg0 only
template<int K, int NOUT, int MODE, int KSPLIT>
__global__ __launch_bounds__(256) void moe_gemm(
    const u16* __restrict__ A, const u16* __restrict__ Wt, const float* __restrict__ bias,
    const int* __restrict__ goff, const int* __restrict__ tok_of_g,
    const float* __restrict__ w_of_g, const int* __restrict__ tiles,
    const int* __restrict__ ntiles,
    u16* __restrict__ Hout, float* __restrict__ Out) {
  const int KLEN = K / KSPLIT;
  int tl = blockIdx.x;
  if (tl >= ntiles[0]) return;
  int packed = tiles[tl];
  int e = packed >> 16;
  int mb = packed & 0xffff;
  int kseg = (KSPLIT > 1) ? blockIdx.z : 0;
  int gb = goff[e];
  int cntE = goff[e + 1] - gb;
  int m0 = mb * 128;
  int mvalid = cntE - m0; if (mvalid > 128) mvalid = 128;
  int gbase = gb + m0;
  int n0 = blockIdx.y * 128;
  int kbeg = kseg * KLEN;
  int tid = threadIdx.x;
  int lane = tid & 63, wave = tid >> 6;

  __shared__ __align__(16) u16 As[128 * 32];   // 8 KB
  __shared__ __align__(16) u16 Bs[128 * 32];

  int sr = lane >> 2;
  int sc = (lane & 3) * 8;
  int ra0 = wave * 16 + sr;
  int ra1 = 64 + wave * 16 + sr;
  int ca0 = (ra0 < mvalid) ? ra0 : (mvalid - 1);
  int ca1 = (ra1 < mvalid) ? ra1 : (mvalid - 1);
  const u16 *pa0, *pa1;
  if (MODE == 0) {
    pa0 = A + (size_t)tok_of_g[gbase + ca0] * K + sc;
    pa1 = A + (size_t)tok_of_g[gbase + ca1] * K + sc;
  } else {
    pa0 = A + (size_t)(gbase + ca0) * K + sc;
    pa1 = A + (size_t)(gbase + ca1) * K + sc;
  }
  const u16* wte = Wt + (size_t)e * NOUT * K;
  const u16* pb0 = wte + (size_t)(n0 + ra0) * K + sc;
  const u16* pb1 = wte + (size_t)(n0 + ra1) * K + sc;
  u16* ldsA0 = As + wave * 512;
  u16* ldsA1 = As + 2048 + wave * 512;
  u16* ldsB0 = Bs + wave * 512;
  u16* ldsB1 = Bs + 2048 + wave * 512;

  int wm = wave >> 1, wn = wave & 1;
  int lr = lane & 15, lk = (lane >> 4) * 8;

  floatx4 acc[4][4];
#pragma unroll
  for (int i = 0; i < 4; i++)
#pragma unroll
    for (int j = 0; j < 4; j++) acc[i][j] = (floatx4){0.f, 0.f, 0.f, 0.f};

  for (int k0 = kbeg; k0 < kbeg + KLEN; k0 += 32) {
    __syncthreads();
    async_cp16(pa0 + k0, ldsA0);
    async_cp16(pa1 + k0, ldsA1);
    async_cp16(pb0 + k0, ldsB0);
    async_cp16(pb1 + k0, ldsB1);
    __syncthreads();
    shortx8 af[4], bfr[4];
#pragma unroll
    for (int i = 0; i < 4; i++) {
      af[i]  = *(const shortx8*)&As[(wm * 64 + i * 16 + lr) * 32 + lk];
      bfr[i] = *(const shortx8*)&Bs[(wn * 64 + i * 16 + lr) * 32 + lk];
    }
#pragma unroll
    for (int i = 0; i < 4; i++)
#pragma unroll
      for (int j = 0; j < 4; j++)
        acc[i][j] = __builtin_amdgcn_mfma_f32_16x16x32_bf16(af[i], bfr[j], acc[i][j], 0, 0, 0);
  }

  const float* bp = bias + (size_t)e * NOUT + n0;
  if (MODE == 0) {
#pragma unroll
    for (int i = 0; i < 4; i++) {
      int rowb = wm * 64 + i * 16 + (lane >> 4) * 4;
#pragma unroll
      for (int r = 0; r < 4; r++) {
        int grow = rowb + r;
        if (grow < mvalid) {
          size_t base = (size_t)(gbase + grow) * NOUT + n0;
#pragma unroll
          for (int j = 0; j < 4; j++) {
            int col = wn * 64 + j * 16 + lr;
            float v = acc[i][j][r] + bp[col];
            v = 0.5f * v * (1.f + erff(v * 0.70710678118654752f));  // exact gelu
            Hout[base + col] = f2bf(v);
          }
        }
      }
    }
  } else {
#pragma unroll
    for (int i = 0; i < 4; i++) {
      int rowb = wm * 64 + i * 16 + (lane >> 4) * 4;
#pragma unroll
      for (int r = 0; r < 4; r++) {
        int grow = rowb + r;
        if (grow < mvalid) {
          int gi = gbase + grow;
          int t = tok_of_g[gi];
          float wg = w_of_g[gi];
          float* orow = Out + (size_t)t * DM + n0;
#pragma unroll
          for (int j = 0; j < 4; j++) {
            int col = wn * 64 + j * 16 + lr;
            float bb = (kseg == 0) ? bp[col] : 0.f;
            atomicAdd(&orow[col], wg * (acc[i][j][r] + bb));
          }
        }
      }
    }
  }
}

extern "C" void kernel_launch(void* const* d_in, const int* in_sizes, int n_in,
                              void* d_out, int out_size, void* d_ws, size_t ws_size,
                              hipStream_t stream) {
  const float* x  = (const float*)d_in[0];
  const float* gw = (const float*)d_in[1];
  const float* w1 = (const float*)d_in[2];
  const float* b1 = (const float*)d_in[3];
  const float* w2 = (const float*)d_in[4];
  const float* b2 = (const float*)d_in[5];
  float* out = (float*)d_out;
  char* ws = (char*)d_ws;

  u16* xb = (u16*)(ws + 0);                       // 8 MB
  u16* wt = (u16*)(ws + 8388608);                 // 64 MB (w1t, then w2t)
  u16* h  = (u16*)(ws + 75497472);                // 64 MB
  char* meta = ws + 142606336;
  int*   eos      = (int*)(meta);
  int*   tok_of_g = (int*)(meta + 32768);
  float* wos      = (float*)(meta + 65536);
  float* w_of_g   = (float*)(meta + 98304);
  int*   goff     = (int*)(meta + 131072);
  int*   tiles    = (int*)(meta + 131200);
  int*   ntiles   = (int*)(meta + 131584);

  hipMemsetAsync(out, 0, (size_t)NTOK * DM * 4, stream);

  cvt_x_kernel<<<NTOK * DM / 8 / 256, 256, 0, stream>>>(x, xb);
  transpose_kernel<DM, DH><<<dim3(DH / 64, DM / 64, NE), 256, 0, stream>>>(w1, wt);
  router_kernel<<<NTOK / 4, 256, 0, stream>>>(x, gw, eos, wos);
  build_groups_kernel<<<1, 256, 0, stream>>>(eos, wos, goff, tok_of_g, w_of_g, tiles, ntiles);
  // GEMM1: compacted tiles (x, fastest: B-tile shared), 32 nb (y)
  moe_gemm<DM, DH, 0, 1><<<dim3(TMAX, DH / 128, 1), 256, 0, stream>>>(
      xb, wt, b1, goff, tok_of_g, w_of_g, tiles, ntiles, h, nullptr);
  transpose_kernel<DH, DM><<<dim3(DM / 64, DH / 64, NE), 256, 0, stream>>>(w2, wt);
  // GEMM2: compacted tiles, 8 nb, split-K x2
  moe_gemm<DH, DM, 1, 2><<<dim3(TMAX, DM / 128, 2), 256, 0, stream>>>(
      h, wt, b2, goff, tok_of_g, w_of_g, tiles, ntiles, nullptr, out);
}